// Round 15
// baseline (400.902 us; speedup 1.0000x reference)
//
#include <hip/hip_runtime.h>
#include <hip/hip_fp16.h>

#define NN 100000
#define NE 3200000
#define NG 128
#define BN_EPS 1e-5f

#define NBUK 782          // ceil(100000 / 128)
#define BSHIFT 7          // bucket = dst >> 7 (128 nodes per bucket)
#define BCAP 6144         // slab capacity per bucket (mean 4096, +32 sigma)

#define GRID_SG 1024      // persistent blocks, 4/CU
#define PBMAX 2048        // partial-buffer column stride
#define PSLICE 8          // pool slices per graph

typedef _Float16 h2v __attribute__((ext_vector_type(2)));
typedef unsigned int u32x2 __attribute__((ext_vector_type(2)));
typedef unsigned int u32x4 __attribute__((ext_vector_type(4)));

// Lessons ledger:
// r9: no grid-wide spin barriers (occupancy halved -> 2.5x slower).
// r10: no __threadfence/agent-fences in L2-resident gather kernels.
// r12: nt ONLY for full-line write-once streams / read-once streams.
// r13: consumers of nt-written data need high block-level parallelism.
// r14: FETCH_SIZE == L2-miss traffic (L3-served counts too); the 12.8MB table
//      runs at ~62% L2 hit -- bnrelu's "L2 warming" was illusory, so BN+ReLU
//      is folded into the gather (r15) and the post-BN table eliminated.

// ---------------- bucketed edge scatter (counting-sort level 1) ----------------
__global__ void __launch_bounds__(512) k_scatter(
    const int* __restrict__ src, const int* __restrict__ dst,
    int* __restrict__ slab_cursor, unsigned int* __restrict__ slab, int E) {
    __shared__ int hist[NBUK + 2];
    __shared__ int cbase[NBUK + 2];
    int tid = threadIdx.x;
    int eBeg = blockIdx.x * 6250;
    int eEnd = min(eBeg + 6250, E);

    for (int t = tid; t < NBUK; t += 512) hist[t] = 0;
    __syncthreads();
    for (int e = eBeg + tid; e < eEnd; e += 512) {
        int b = dst[e] >> BSHIFT;
        atomicAdd(&hist[b], 1);
    }
    __syncthreads();
    for (int t = tid; t < NBUK; t += 512) {
        int c = hist[t];
        cbase[t] = (c > 0) ? atomicAdd(&slab_cursor[t], c) : 0;
    }
    __syncthreads();
    for (int t = tid; t < NBUK; t += 512) hist[t] = 0;
    __syncthreads();
    for (int e = eBeg + tid; e < eEnd; e += 512) {
        int d = dst[e];
        int b = d >> BSHIFT;
        int r = atomicAdd(&hist[b], 1);
        int pos = cbase[b] + r;
        if (pos < BCAP) slab[(size_t)b * BCAP + pos] = ((unsigned)src[e] << BSHIFT) | (unsigned)(d & 127);
    }
}

// ---------------- per-bucket CSR build + FUSED LAYER 1 (scan folded in) ----------------
__global__ void __launch_bounds__(512) k_bucket_csr(
    const unsigned int* __restrict__ slab, const int* __restrict__ slab_cursor,
    int* __restrict__ row_ptr,
    float* __restrict__ deg_inv, int* __restrict__ csr_src,
    const float* __restrict__ x, const float* __restrict__ w1l,
    const float* __restrict__ b1, const float* __restrict__ w1r,
    __half* __restrict__ hp16, float* __restrict__ part) {
    __shared__ int lds_csr[BCAP];
    __shared__ int red[512];
    __shared__ int sdeg[128];
    __shared__ int sscan[128];
    __shared__ int slcur[128];
    __shared__ float swl[256], swr[256], sb1[64];
    __shared__ float ssum[64], ssq[64];
    int tid = threadIdx.x;
    int b = blockIdx.x;
    int lo = b << BSHIFT;
    int cnt = min(slab_cursor[b], BCAP);
    const unsigned int* sl = slab + (size_t)b * BCAP;

    // inline exclusive prefix over bucket counts
    int partial = 0;
    for (int j = tid; j < b; j += 512) partial += min(slab_cursor[j], BCAP);
    red[tid] = partial;
    __syncthreads();
    for (int off = 256; off > 0; off >>= 1) {
        if (tid < off) red[tid] += red[tid + off];
        __syncthreads();
    }
    int base = red[0];
    if (b == NBUK - 1 && tid == 0) row_ptr[NN] = base + cnt;

    if (tid < 256) { swl[tid] = w1l[tid]; swr[tid] = w1r[tid]; }
    if (tid < 64)  { sb1[tid] = b1[tid]; ssum[tid] = 0.f; ssq[tid] = 0.f; }
    if (tid < 128) sdeg[tid] = 0;
    __syncthreads();
    for (int k = tid; k < cnt; k += 512) {
        atomicAdd(&sdeg[sl[k] & 127], 1);
    }
    __syncthreads();
    int v = (tid < 128) ? sdeg[tid] : 0;
    if (tid < 128) sscan[tid] = v;
    __syncthreads();
    for (int off = 1; off < 128; off <<= 1) {
        int add = 0;
        if (tid < 128 && tid >= off) add = sscan[tid - off];
        __syncthreads();
        if (tid < 128) sscan[tid] += add;
        __syncthreads();
    }
    if (tid < 128) {
        int excl = sscan[tid] - v;
        int n = lo + tid;
        if (n < NN) {
            row_ptr[n] = base + excl;
            deg_inv[n] = 1.0f / fmaxf((float)v, 1.0f);
        }
        slcur[tid] = excl;   // LOCAL cursor
    }
    __syncthreads();
    for (int k = tid; k < cnt; k += 512) {
        unsigned int p = sl[k];
        int pos = atomicAdd(&slcur[p & 127], 1);
        lds_csr[pos] = (int)(p >> BSHIFT);
    }
    __syncthreads();
    // cached store: csr_src re-read by both k_sage layers
    for (int k = tid; k < cnt; k += 512) csr_src[base + k] = lds_csr[k];

    // ---- Phase B: layer 1 ----
    int i = tid >> 2, c = tid & 3;
    int n = lo + i;
    bool valid = (n < NN);
    int dhi = sscan[i];
    int dlo = dhi - sdeg[i];
    const float4* x4 = (const float4*)x;
    float4 acc = make_float4(0.f, 0.f, 0.f, 0.f);
    for (int k = dlo + c; k < dhi; k += 4) {
        int s = lds_csr[k];
        float4 xv = x4[s];
        acc.x += xv.x; acc.y += xv.y; acc.z += xv.z; acc.w += xv.w;
    }
#pragma unroll
    for (int m = 1; m <= 2; m <<= 1) {
        acc.x += __shfl_xor(acc.x, m);
        acc.y += __shfl_xor(acc.y, m);
        acc.z += __shfl_xor(acc.z, m);
        acc.w += __shfl_xor(acc.w, m);
    }
    float dv = 1.0f / fmaxf((float)sdeg[i], 1.0f);
    float ax = acc.x * dv, ay = acc.y * dv, az = acc.z * dv, aw = acc.w * dv;
    float4 xs = valid ? x4[n] : make_float4(0.f, 0.f, 0.f, 0.f);

#pragma unroll
    for (int m4 = 0; m4 < 4; m4++) {
        float4 o = make_float4(0.f, 0.f, 0.f, 0.f);
        float* op = &o.x;
        if (valid) {
#pragma unroll
            for (int t = 0; t < 4; t++) {
                int j = c * 16 + m4 * 4 + t;
                float s = sb1[j];
                s += ax * swl[j * 4 + 0] + ay * swl[j * 4 + 1] + az * swl[j * 4 + 2] + aw * swl[j * 4 + 3];
                s += xs.x * swr[j * 4 + 0] + xs.y * swr[j * 4 + 1] + xs.z * swr[j * 4 + 2] + xs.w * swr[j * 4 + 3];
                op[t] = s;
            }
            h2v p0 = h2v{(_Float16)o.x, (_Float16)o.y};
            h2v p1 = h2v{(_Float16)o.z, (_Float16)o.w};
            u32x2 w;
            w.x = *(unsigned int*)&p0;
            w.y = *(unsigned int*)&p1;
            __builtin_nontemporal_store(w, (u32x2*)hp16 + (size_t)n * 16 + c * 4 + m4);
        }
        float4 q = make_float4(o.x * o.x, o.y * o.y, o.z * o.z, o.w * o.w);
#pragma unroll
        for (int m = 4; m <= 32; m <<= 1) {
            o.x += __shfl_xor(o.x, m); o.y += __shfl_xor(o.y, m);
            o.z += __shfl_xor(o.z, m); o.w += __shfl_xor(o.w, m);
            q.x += __shfl_xor(q.x, m); q.y += __shfl_xor(q.y, m);
            q.z += __shfl_xor(q.z, m); q.w += __shfl_xor(q.w, m);
        }
        if ((tid & 63) < 4) {
            int jb = c * 16 + m4 * 4;
            atomicAdd(&ssum[jb + 0], o.x); atomicAdd(&ssum[jb + 1], o.y);
            atomicAdd(&ssum[jb + 2], o.z); atomicAdd(&ssum[jb + 3], o.w);
            atomicAdd(&ssq[jb + 0], q.x);  atomicAdd(&ssq[jb + 1], q.y);
            atomicAdd(&ssq[jb + 2], q.z);  atomicAdd(&ssq[jb + 3], q.w);
        }
    }
    __syncthreads();
    if (tid < 64) {
        part[(2 * tid) * PBMAX + blockIdx.x]     = ssum[tid];
        part[(2 * tid + 1) * PBMAX + blockIdx.x] = ssq[tid];
    }
}

// ---------------- fused SAGE layer: BN+ReLU applied in-gather (pre-BN input table) ----------------
// h_in holds PRE-BN activations of the previous layer; sbv_in its BN scale/bias.
// Each gathered element: ReLU(v*sc+bi) before aggregation -> bnrelu pass eliminated.
__global__ void __launch_bounds__(512, 8) k_sage(
    const __half* __restrict__ h_in, const float* __restrict__ sbv_in,
    const int* __restrict__ row_ptr,
    const int* __restrict__ csr_src, const float* __restrict__ deg_inv,
    const float* __restrict__ wl, const float* __restrict__ bl,
    const float* __restrict__ wr, __half* __restrict__ hp16,
    float* __restrict__ part) {
    __shared__ h2v wl2s[32][68];   // [k-pair][out-channel]
    __shared__ h2v wr2s[32][68];
    __shared__ h2v tAh[32][36];
    __shared__ h2v tXh[32][36];
    __shared__ float ssum[64], ssq[64];
    int tid = threadIdx.x;
    for (int idx = tid; idx < 2048; idx += 512) {
        int j = idx & 63, kk = idx >> 6;
        float2 l = ((const float2*)wl)[j * 32 + kk];
        float2 r = ((const float2*)wr)[j * 32 + kk];
        wl2s[kk][j] = h2v{(_Float16)l.x, (_Float16)l.y};
        wr2s[kk][j] = h2v{(_Float16)r.x, (_Float16)r.y};
    }
    if (tid < 64) { ssum[tid] = 0.f; ssq[tid] = 0.f; }
    __syncthreads();

    int g = tid & 15, ni = tid >> 4;      // ni in [0,32)
    // per-lane BN constants for channels 4g..4g+3 of the INPUT layer
    float sc0 = sbv_in[4 * g + 0], sc1 = sbv_in[4 * g + 1];
    float sc2 = sbv_in[4 * g + 2], sc3 = sbv_in[4 * g + 3];
    float bi0 = sbv_in[64 + 4 * g + 0], bi1 = sbv_in[64 + 4 * g + 1];
    float bi2 = sbv_in[64 + 4 * g + 2], bi3 = sbv_in[64 + 4 * g + 3];

    const uint2* tbl = (const uint2*)h_in;
    const int ntiles = NN / 32;           // 3125 exactly

#define BN_ACC(vv) { \
        float2 f0 = __half22float2(*(__half2*)&vv.x); \
        float2 f1 = __half22float2(*(__half2*)&vv.y); \
        ax += fmaxf(f0.x * sc0 + bi0, 0.f); \
        ay += fmaxf(f0.y * sc1 + bi1, 0.f); \
        az += fmaxf(f1.x * sc2 + bi2, 0.f); \
        aw += fmaxf(f1.y * sc3 + bi3, 0.f); }

    for (int tile = blockIdx.x; tile < ntiles; tile += GRID_SG) {
        int n = tile * 32 + ni;
        float ax = 0.f, ay = 0.f, az = 0.f, aw = 0.f;
        int r0 = row_ptr[n], r1 = row_ptr[n + 1];
        int e = r0;
        for (; e + 8 <= r1; e += 8) {
            int s0 = csr_src[e],     s1 = csr_src[e + 1], s2 = csr_src[e + 2], s3 = csr_src[e + 3];
            int s4 = csr_src[e + 4], s5 = csr_src[e + 5], s6 = csr_src[e + 6], s7 = csr_src[e + 7];
            uint2 v0 = tbl[(size_t)s0 * 16 + g];
            uint2 v1 = tbl[(size_t)s1 * 16 + g];
            uint2 v2 = tbl[(size_t)s2 * 16 + g];
            uint2 v3 = tbl[(size_t)s3 * 16 + g];
            uint2 v4 = tbl[(size_t)s4 * 16 + g];
            uint2 v5 = tbl[(size_t)s5 * 16 + g];
            uint2 v6 = tbl[(size_t)s6 * 16 + g];
            uint2 v7 = tbl[(size_t)s7 * 16 + g];
            BN_ACC(v0) BN_ACC(v1) BN_ACC(v2) BN_ACC(v3)
            BN_ACC(v4) BN_ACC(v5) BN_ACC(v6) BN_ACC(v7)
        }
        for (; e < r1; ++e) {
            int s = csr_src[e];
            uint2 vv = tbl[(size_t)s * 16 + g];
            BN_ACC(vv)
        }
        float di = deg_inv[n];
        uint2 rsv = tbl[(size_t)n * 16 + g];
        float2 s0f = __half22float2(*(__half2*)&rsv.x);
        float2 s1f = __half22float2(*(__half2*)&rsv.y);
        float xs0 = fmaxf(s0f.x * sc0 + bi0, 0.f);
        float xs1 = fmaxf(s0f.y * sc1 + bi1, 0.f);
        float xs2 = fmaxf(s1f.x * sc2 + bi2, 0.f);
        float xs3 = fmaxf(s1f.y * sc3 + bi3, 0.f);
        ax *= di; ay *= di; az *= di; aw *= di;
        tAh[ni][2 * g]     = h2v{(_Float16)ax, (_Float16)ay};
        tAh[ni][2 * g + 1] = h2v{(_Float16)az, (_Float16)aw};
        tXh[ni][2 * g]     = h2v{(_Float16)xs0, (_Float16)xs1};
        tXh[ni][2 * g + 1] = h2v{(_Float16)xs2, (_Float16)xs3};
        __syncthreads();

        float4 o = ((const float4*)bl)[g];
#pragma unroll 4
        for (int kk = 0; kk < 32; kk++) {
            h2v a2 = tAh[ni][kk];
            h2v x2 = tXh[ni][kk];
            h2v l0 = wl2s[kk][4 * g + 0], l1 = wl2s[kk][4 * g + 1];
            h2v l2 = wl2s[kk][4 * g + 2], l3 = wl2s[kk][4 * g + 3];
            h2v r0v = wr2s[kk][4 * g + 0], r1v = wr2s[kk][4 * g + 1];
            h2v r2v = wr2s[kk][4 * g + 2], r3v = wr2s[kk][4 * g + 3];
#if __has_builtin(__builtin_amdgcn_fdot2)
            o.x = __builtin_amdgcn_fdot2(a2, l0, o.x, false);
            o.y = __builtin_amdgcn_fdot2(a2, l1, o.y, false);
            o.z = __builtin_amdgcn_fdot2(a2, l2, o.z, false);
            o.w = __builtin_amdgcn_fdot2(a2, l3, o.w, false);
            o.x = __builtin_amdgcn_fdot2(x2, r0v, o.x, false);
            o.y = __builtin_amdgcn_fdot2(x2, r1v, o.y, false);
            o.z = __builtin_amdgcn_fdot2(x2, r2v, o.z, false);
            o.w = __builtin_amdgcn_fdot2(x2, r3v, o.w, false);
#else
            float b0 = (float)a2.x, b1 = (float)a2.y, x0 = (float)x2.x, x1 = (float)x2.y;
            o.x += b0 * (float)l0.x + b1 * (float)l0.y + x0 * (float)r0v.x + x1 * (float)r0v.y;
            o.y += b0 * (float)l1.x + b1 * (float)l1.y + x0 * (float)r1v.x + x1 * (float)r1v.y;
            o.z += b0 * (float)l2.x + b1 * (float)l2.y + x0 * (float)r2v.x + x1 * (float)r2v.y;
            o.w += b0 * (float)l3.x + b1 * (float)l3.y + x0 * (float)r3v.x + x1 * (float)r3v.y;
#endif
        }
        {
            h2v p0 = h2v{(_Float16)o.x, (_Float16)o.y};
            h2v p1 = h2v{(_Float16)o.z, (_Float16)o.w};
            u32x2 w;
            w.x = *(unsigned int*)&p0;
            w.y = *(unsigned int*)&p1;
            __builtin_nontemporal_store(w, (u32x2*)hp16 + (size_t)n * 16 + g);
        }

        float4 qv = make_float4(o.x * o.x, o.y * o.y, o.z * o.z, o.w * o.w);
#pragma unroll
        for (int m = 16; m <= 32; m <<= 1) {
            o.x += __shfl_xor(o.x, m); o.y += __shfl_xor(o.y, m);
            o.z += __shfl_xor(o.z, m); o.w += __shfl_xor(o.w, m);
            qv.x += __shfl_xor(qv.x, m); qv.y += __shfl_xor(qv.y, m);
            qv.z += __shfl_xor(qv.z, m); qv.w += __shfl_xor(qv.w, m);
        }
        if ((tid & 48) == 0) {
            atomicAdd(&ssum[4 * g + 0], o.x); atomicAdd(&ssum[4 * g + 1], o.y);
            atomicAdd(&ssum[4 * g + 2], o.z); atomicAdd(&ssum[4 * g + 3], o.w);
            atomicAdd(&ssq[4 * g + 0], qv.x);  atomicAdd(&ssq[4 * g + 1], qv.y);
            atomicAdd(&ssq[4 * g + 2], qv.z);  atomicAdd(&ssq[4 * g + 3], qv.w);
        }
        __syncthreads();   // protect tAh/tXh for next tile
    }
#undef BN_ACC
    if (tid < 64) {
        part[(2 * tid) * PBMAX + blockIdx.x]     = ssum[tid];
        part[(2 * tid + 1) * PBMAX + blockIdx.x] = ssq[tid];
    }
}

// ---------------- reduce partials -> BN scale/bias ----------------
__global__ void k_reduce_sb(const float* __restrict__ part, int PB,
                            const float* __restrict__ gamma, const float* __restrict__ beta,
                            float* __restrict__ sbv, int N) {
    int c = blockIdx.x;
    float s = 0.f, q = 0.f;
    for (int b = threadIdx.x; b < PB; b += 256) {
        s += part[(2 * c) * PBMAX + b];
        q += part[(2 * c + 1) * PBMAX + b];
    }
    __shared__ float rs[256], rq[256];
    rs[threadIdx.x] = s;
    rq[threadIdx.x] = q;
    __syncthreads();
    for (int off = 128; off > 0; off >>= 1) {
        if (threadIdx.x < off) {
            rs[threadIdx.x] += rs[threadIdx.x + off];
            rq[threadIdx.x] += rq[threadIdx.x + off];
        }
        __syncthreads();
    }
    if (threadIdx.x == 0) {
        float m = rs[0] / (float)N;
        float var = rq[0] / (float)N - m * m;
        float sc = gamma[c] * rsqrtf(var + BN_EPS);
        sbv[c]      = sc;
        sbv[64 + c] = beta[c] - m * sc;
    }
}

// ---------------- pool partials: 8 slices x 128 graphs, BN3+ReLU inline ----------------
__global__ void __launch_bounds__(256) k_pool_partial(
    const __half* __restrict__ hp16, const float* __restrict__ sbv,
    const int* __restrict__ batch, float* __restrict__ pooled_part, int N) {
    __shared__ float ssc[64], sbi[64];
    __shared__ float sm[256];
    if (threadIdx.x < 64) {
        ssc[threadIdx.x] = sbv[threadIdx.x];
        sbi[threadIdx.x] = sbv[64 + threadIdx.x];
    }
    __syncthreads();
    int gph = blockIdx.x >> 3;        // 128 graphs
    int slice = blockIdx.x & 7;       // 8 slices
    int lo = 0, hi = N;
    while (lo < hi) { int mid = (lo + hi) >> 1; if (batch[mid] < gph) lo = mid + 1; else hi = mid; }
    int start = lo;
    hi = N;
    while (lo < hi) { int mid = (lo + hi) >> 1; if (batch[mid] < gph + 1) lo = mid + 1; else hi = mid; }
    int end = lo;

    int c = threadIdx.x & 63, w = threadIdx.x >> 6;   // 4 walkers/block, 32 grid-wide/graph
    float s = 0.f;
    for (int r = start + slice * 4 + w; r < end; r += 32)
        s += fmaxf(__half2float(hp16[(size_t)r * 64 + c]) * ssc[c] + sbi[c], 0.f);
    sm[threadIdx.x] = s;
    __syncthreads();
    if (threadIdx.x < 64) {
        float t = sm[c] + sm[64 + c] + sm[128 + c] + sm[192 + c];
        pooled_part[(size_t)(gph * PSLICE + slice) * 64 + c] = t;
    }
}

// ---------------- head: fold slice partials + MLP ----------------
__global__ void __launch_bounds__(64) k_head(
    const float* __restrict__ pooled_part, const int* __restrict__ batch,
    const float* __restrict__ fc1w, const float* __restrict__ fc1b,
    const float* __restrict__ fc2w, const float* __restrict__ fc2b,
    float* __restrict__ out, int N) {
    __shared__ float pl[64], hid[64];
    int gph = blockIdx.x;
    int j = threadIdx.x;
    int lo = 0, hi = N;
    while (lo < hi) { int mid = (lo + hi) >> 1; if (batch[mid] < gph) lo = mid + 1; else hi = mid; }
    int start = lo;
    hi = N;
    while (lo < hi) { int mid = (lo + hi) >> 1; if (batch[mid] < gph + 1) lo = mid + 1; else hi = mid; }
    int cnt = lo - start;

    float t = 0.f;
#pragma unroll
    for (int s = 0; s < PSLICE; s++) t += pooled_part[(size_t)(gph * PSLICE + s) * 64 + j];
    pl[j] = t / fmaxf((float)cnt, 1.0f);
    __syncthreads();
    float v = fc1b[j];
    for (int k = 0; k < 64; k++) v += pl[k] * fc1w[j * 64 + k];
    hid[j] = fmaxf(v, 0.f);
    __syncthreads();
    if (j < 2) {
        float o = fc2b[j];
        for (int k = 0; k < 64; k++) o += hid[k] * fc2w[j * 64 + k];
        out[gph * 2 + j] = o;
    }
}

extern "C" void kernel_launch(void* const* d_in, const int* in_sizes, int n_in,
                              void* d_out, int out_size, void* d_ws, size_t ws_size,
                              hipStream_t stream) {
    const float* x    = (const float*)d_in[0];
    const int* ei     = (const int*)d_in[1];
    const int* batch  = (const int*)d_in[2];
    const float* w1l  = (const float*)d_in[3];
    const float* b1   = (const float*)d_in[4];
    const float* w1r  = (const float*)d_in[5];
    const float* bn1g = (const float*)d_in[6];
    const float* bn1b = (const float*)d_in[7];
    const float* w2l  = (const float*)d_in[8];
    const float* b2   = (const float*)d_in[9];
    const float* w2r  = (const float*)d_in[10];
    const float* bn2g = (const float*)d_in[11];
    const float* bn2b = (const float*)d_in[12];
    const float* w3l  = (const float*)d_in[13];
    const float* b3   = (const float*)d_in[14];
    const float* w3r  = (const float*)d_in[15];
    const float* bn3g = (const float*)d_in[16];
    const float* bn3b = (const float*)d_in[17];
    const float* fc1w = (const float*)d_in[18];
    const float* fc1b = (const float*)d_in[19];
    const float* fc2w = (const float*)d_in[20];
    const float* fc2b = (const float*)d_in[21];
    float* out = (float*)d_out;

    const int N = NN, E = NE;
    const int* srcp = ei;
    const int* dstp = ei + E;

    char* ws = (char*)d_ws;
    size_t off = 0;
    auto alloc = [&](size_t bytes) -> char* {
        char* p = ws + off;
        off += (bytes + 255) & ~(size_t)255;
        return p;
    };
    int* csr_src       = (int*)alloc(sizeof(int) * E);
    __half* hpA        = (__half*)alloc(sizeof(__half) * N * 64); // pre-BN fp16 ping
    __half* hpB        = (__half*)alloc(sizeof(__half) * N * 64); // pre-BN fp16 pong
    unsigned int* slab = (unsigned int*)alloc(sizeof(unsigned int) * (size_t)NBUK * BCAP);
    int* slab_cursor   = (int*)alloc(sizeof(int) * NBUK);
    int* row_ptr       = (int*)alloc(sizeof(int) * (N + 1));
    float* deg_inv     = (float*)alloc(sizeof(float) * N);
    float* part        = (float*)alloc(sizeof(float) * 128 * PBMAX);
    float* sbv         = (float*)alloc(sizeof(float) * 128);
    float* pooled_part = (float*)alloc(sizeof(float) * NG * PSLICE * 64);

    hipMemsetAsync(slab_cursor, 0, sizeof(int) * NBUK, stream);

    // ---- CSR build + fused layer 1 -> hpA (pre-BN1) ----
    k_scatter<<<512, 512, 0, stream>>>(srcp, dstp, slab_cursor, slab, E);
    k_bucket_csr<<<NBUK, 512, 0, stream>>>(slab, slab_cursor, row_ptr, deg_inv,
                                           csr_src, x, w1l, b1, w1r, hpA, part);
    k_reduce_sb<<<64, 256, 0, stream>>>(part, NBUK, bn1g, bn1b, sbv, N);

    // layer 2: BN1+ReLU in-gather from hpA -> hpB (pre-BN2)
    k_sage<<<GRID_SG, 512, 0, stream>>>(hpA, sbv, row_ptr, csr_src, deg_inv,
                                        w2l, b2, w2r, hpB, part);
    k_reduce_sb<<<64, 256, 0, stream>>>(part, GRID_SG, bn2g, bn2b, sbv, N);

    // layer 3: BN2+ReLU in-gather from hpB -> hpA (pre-BN3)
    k_sage<<<GRID_SG, 512, 0, stream>>>(hpB, sbv, row_ptr, csr_src, deg_inv,
                                        w3l, b3, w3r, hpA, part);
    k_reduce_sb<<<64, 256, 0, stream>>>(part, GRID_SG, bn3g, bn3b, sbv, N);

    // pool (BN3+ReLU inline) + head
    k_pool_partial<<<NG * PSLICE, 256, 0, stream>>>(hpA, sbv, batch, pooled_part, N);
    k_head<<<NG, 64, 0, stream>>>(pooled_part, batch, fc1w, fc1b, fc2w, fc2b, out, N);
}

// Round 17
// 394.370 us; speedup vs baseline: 1.0166x; 1.0166x over previous
//
#include <hip/hip_runtime.h>
#include <hip/hip_fp16.h>

#define NN 100000
#define NE 3200000
#define NG 128
#define BN_EPS 1e-5f

#define NBUK 782          // ceil(100000 / 128)
#define BSHIFT 7          // bucket = dst >> 7 (128 nodes per bucket)
#define BCAP 6144         // slab capacity per bucket (mean 4096, +32 sigma)

#define GRID_SG 1024      // persistent blocks, 4/CU
#define PBMAX 2048        // partial-buffer column stride
#define PSLICE 8          // pool slices per graph

typedef _Float16 h2v __attribute__((ext_vector_type(2)));
typedef unsigned int u32x2 __attribute__((ext_vector_type(2)));
typedef unsigned int u32x4 __attribute__((ext_vector_type(4)));

// Lessons ledger:
// r9: no grid-wide spin barriers (occupancy halved -> 2.5x slower).
// r10: no __threadfence/agent-fences in L2-resident gather kernels.
// r12: nt ONLY for full-line write-once streams / read-once streams.
// r13: consumers of nt-written data need high block-level parallelism.
// r14: FETCH_SIZE == L2-miss traffic; table runs ~60% L2-hit equilibrium.
// r15: BN-in-gather dispatch-neutral; scalar BN cost ~11us VALU on critical path.
// r16: __hmax2 not in ROCm 7.2 headers -> use native h2v vector ops +
//      __builtin_elementwise_max (lowers to v_pk_fma_f16 / v_pk_max_f16).

// ---------------- bucketed edge scatter (counting-sort level 1) ----------------
__global__ void __launch_bounds__(512) k_scatter(
    const int* __restrict__ src, const int* __restrict__ dst,
    int* __restrict__ slab_cursor, unsigned int* __restrict__ slab, int E) {
    __shared__ int hist[NBUK + 2];
    __shared__ int cbase[NBUK + 2];
    int tid = threadIdx.x;
    int eBeg = blockIdx.x * 6250;
    int eEnd = min(eBeg + 6250, E);

    for (int t = tid; t < NBUK; t += 512) hist[t] = 0;
    __syncthreads();
    for (int e = eBeg + tid; e < eEnd; e += 512) {
        int b = dst[e] >> BSHIFT;
        atomicAdd(&hist[b], 1);
    }
    __syncthreads();
    for (int t = tid; t < NBUK; t += 512) {
        int c = hist[t];
        cbase[t] = (c > 0) ? atomicAdd(&slab_cursor[t], c) : 0;
    }
    __syncthreads();
    for (int t = tid; t < NBUK; t += 512) hist[t] = 0;
    __syncthreads();
    for (int e = eBeg + tid; e < eEnd; e += 512) {
        int d = dst[e];
        int b = d >> BSHIFT;
        int r = atomicAdd(&hist[b], 1);
        int pos = cbase[b] + r;
        if (pos < BCAP) slab[(size_t)b * BCAP + pos] = ((unsigned)src[e] << BSHIFT) | (unsigned)(d & 127);
    }
}

// ---------------- per-bucket CSR build + FUSED LAYER 1 (scan folded in) ----------------
__global__ void __launch_bounds__(512) k_bucket_csr(
    const unsigned int* __restrict__ slab, const int* __restrict__ slab_cursor,
    int* __restrict__ row_ptr,
    float* __restrict__ deg_inv, int* __restrict__ csr_src,
    const float* __restrict__ x, const float* __restrict__ w1l,
    const float* __restrict__ b1, const float* __restrict__ w1r,
    __half* __restrict__ hp16, float* __restrict__ part) {
    __shared__ int lds_csr[BCAP];
    __shared__ int red[512];
    __shared__ int sdeg[128];
    __shared__ int sscan[128];
    __shared__ int slcur[128];
    __shared__ float swl[256], swr[256], sb1[64];
    __shared__ float ssum[64], ssq[64];
    int tid = threadIdx.x;
    int b = blockIdx.x;
    int lo = b << BSHIFT;
    int cnt = min(slab_cursor[b], BCAP);
    const unsigned int* sl = slab + (size_t)b * BCAP;

    // inline exclusive prefix over bucket counts
    int partial = 0;
    for (int j = tid; j < b; j += 512) partial += min(slab_cursor[j], BCAP);
    red[tid] = partial;
    __syncthreads();
    for (int off = 256; off > 0; off >>= 1) {
        if (tid < off) red[tid] += red[tid + off];
        __syncthreads();
    }
    int base = red[0];
    if (b == NBUK - 1 && tid == 0) row_ptr[NN] = base + cnt;

    if (tid < 256) { swl[tid] = w1l[tid]; swr[tid] = w1r[tid]; }
    if (tid < 64)  { sb1[tid] = b1[tid]; ssum[tid] = 0.f; ssq[tid] = 0.f; }
    if (tid < 128) sdeg[tid] = 0;
    __syncthreads();
    for (int k = tid; k < cnt; k += 512) {
        atomicAdd(&sdeg[sl[k] & 127], 1);
    }
    __syncthreads();
    int v = (tid < 128) ? sdeg[tid] : 0;
    if (tid < 128) sscan[tid] = v;
    __syncthreads();
    for (int off = 1; off < 128; off <<= 1) {
        int add = 0;
        if (tid < 128 && tid >= off) add = sscan[tid - off];
        __syncthreads();
        if (tid < 128) sscan[tid] += add;
        __syncthreads();
    }
    if (tid < 128) {
        int excl = sscan[tid] - v;
        int n = lo + tid;
        if (n < NN) {
            row_ptr[n] = base + excl;
            deg_inv[n] = 1.0f / fmaxf((float)v, 1.0f);
        }
        slcur[tid] = excl;   // LOCAL cursor
    }
    __syncthreads();
    for (int k = tid; k < cnt; k += 512) {
        unsigned int p = sl[k];
        int pos = atomicAdd(&slcur[p & 127], 1);
        lds_csr[pos] = (int)(p >> BSHIFT);
    }
    __syncthreads();
    // cached store: csr_src re-read by both k_sage layers
    for (int k = tid; k < cnt; k += 512) csr_src[base + k] = lds_csr[k];

    // ---- Phase B: layer 1 (x-gather 4-deep pipelined) ----
    int i = tid >> 2, c = tid & 3;
    int n = lo + i;
    bool valid = (n < NN);
    int dhi = sscan[i];
    int dlo = dhi - sdeg[i];
    const float4* x4 = (const float4*)x;
    float4 acc = make_float4(0.f, 0.f, 0.f, 0.f);
    int k = dlo + c;
    for (; k + 12 < dhi; k += 16) {
        int s0 = lds_csr[k], s1 = lds_csr[k + 4], s2 = lds_csr[k + 8], s3 = lds_csr[k + 12];
        float4 v0 = x4[s0];
        float4 v1 = x4[s1];
        float4 v2 = x4[s2];
        float4 v3 = x4[s3];
        acc.x += v0.x + v1.x + v2.x + v3.x;
        acc.y += v0.y + v1.y + v2.y + v3.y;
        acc.z += v0.z + v1.z + v2.z + v3.z;
        acc.w += v0.w + v1.w + v2.w + v3.w;
    }
    for (; k < dhi; k += 4) {
        int s = lds_csr[k];
        float4 xv = x4[s];
        acc.x += xv.x; acc.y += xv.y; acc.z += xv.z; acc.w += xv.w;
    }
#pragma unroll
    for (int m = 1; m <= 2; m <<= 1) {
        acc.x += __shfl_xor(acc.x, m);
        acc.y += __shfl_xor(acc.y, m);
        acc.z += __shfl_xor(acc.z, m);
        acc.w += __shfl_xor(acc.w, m);
    }
    float dv = 1.0f / fmaxf((float)sdeg[i], 1.0f);
    float ax = acc.x * dv, ay = acc.y * dv, az = acc.z * dv, aw = acc.w * dv;
    float4 xs = valid ? x4[n] : make_float4(0.f, 0.f, 0.f, 0.f);

#pragma unroll
    for (int m4 = 0; m4 < 4; m4++) {
        float4 o = make_float4(0.f, 0.f, 0.f, 0.f);
        float* op = &o.x;
        if (valid) {
#pragma unroll
            for (int t = 0; t < 4; t++) {
                int j = c * 16 + m4 * 4 + t;
                float s = sb1[j];
                s += ax * swl[j * 4 + 0] + ay * swl[j * 4 + 1] + az * swl[j * 4 + 2] + aw * swl[j * 4 + 3];
                s += xs.x * swr[j * 4 + 0] + xs.y * swr[j * 4 + 1] + xs.z * swr[j * 4 + 2] + xs.w * swr[j * 4 + 3];
                op[t] = s;
            }
            h2v p0 = h2v{(_Float16)o.x, (_Float16)o.y};
            h2v p1 = h2v{(_Float16)o.z, (_Float16)o.w};
            u32x2 w;
            w.x = *(unsigned int*)&p0;
            w.y = *(unsigned int*)&p1;
            __builtin_nontemporal_store(w, (u32x2*)hp16 + (size_t)n * 16 + c * 4 + m4);
        }
        float4 q = make_float4(o.x * o.x, o.y * o.y, o.z * o.z, o.w * o.w);
#pragma unroll
        for (int m = 4; m <= 32; m <<= 1) {
            o.x += __shfl_xor(o.x, m); o.y += __shfl_xor(o.y, m);
            o.z += __shfl_xor(o.z, m); o.w += __shfl_xor(o.w, m);
            q.x += __shfl_xor(q.x, m); q.y += __shfl_xor(q.y, m);
            q.z += __shfl_xor(q.z, m); q.w += __shfl_xor(q.w, m);
        }
        if ((tid & 63) < 4) {
            int jb = c * 16 + m4 * 4;
            atomicAdd(&ssum[jb + 0], o.x); atomicAdd(&ssum[jb + 1], o.y);
            atomicAdd(&ssum[jb + 2], o.z); atomicAdd(&ssum[jb + 3], o.w);
            atomicAdd(&ssq[jb + 0], q.x);  atomicAdd(&ssq[jb + 1], q.y);
            atomicAdd(&ssq[jb + 2], q.z);  atomicAdd(&ssq[jb + 3], q.w);
        }
    }
    __syncthreads();
    if (tid < 64) {
        part[(2 * tid) * PBMAX + blockIdx.x]     = ssum[tid];
        part[(2 * tid + 1) * PBMAX + blockIdx.x] = ssq[tid];
    }
}

// ---------------- fused SAGE layer: packed-fp16 BN+ReLU in-gather + dot2 GEMM ----------------
__global__ void __launch_bounds__(512, 8) k_sage(
    const __half* __restrict__ h_in, const float* __restrict__ sbv_in,
    const int* __restrict__ row_ptr,
    const int* __restrict__ csr_src, const float* __restrict__ deg_inv,
    const float* __restrict__ wl, const float* __restrict__ bl,
    const float* __restrict__ wr, __half* __restrict__ hp16,
    float* __restrict__ part) {
    __shared__ h2v wl2s[32][68];   // [k-pair][out-channel]
    __shared__ h2v wr2s[32][68];
    __shared__ h2v tAh[32][36];
    __shared__ h2v tXh[32][36];
    __shared__ float ssum[64], ssq[64];
    int tid = threadIdx.x;
    for (int idx = tid; idx < 2048; idx += 512) {
        int j = idx & 63, kk = idx >> 6;
        float2 l = ((const float2*)wl)[j * 32 + kk];
        float2 r = ((const float2*)wr)[j * 32 + kk];
        wl2s[kk][j] = h2v{(_Float16)l.x, (_Float16)l.y};
        wr2s[kk][j] = h2v{(_Float16)r.x, (_Float16)r.y};
    }
    if (tid < 64) { ssum[tid] = 0.f; ssq[tid] = 0.f; }
    __syncthreads();

    int g = tid & 15, ni = tid >> 4;      // ni in [0,32)
    // packed BN constants for channels 4g..4g+3 of the INPUT layer (native h2v)
    h2v sch0 = h2v{(_Float16)sbv_in[4 * g + 0], (_Float16)sbv_in[4 * g + 1]};
    h2v sch1 = h2v{(_Float16)sbv_in[4 * g + 2], (_Float16)sbv_in[4 * g + 3]};
    h2v bih0 = h2v{(_Float16)sbv_in[64 + 4 * g + 0], (_Float16)sbv_in[64 + 4 * g + 1]};
    h2v bih1 = h2v{(_Float16)sbv_in[64 + 4 * g + 2], (_Float16)sbv_in[64 + 4 * g + 3]};
    h2v hz = h2v{(_Float16)0.f, (_Float16)0.f};

    const uint2* tbl = (const uint2*)h_in;
    const int ntiles = NN / 32;           // 3125 exactly

    // packed BN+ReLU: v_pk_fma_f16 + v_pk_max_f16, then f32 accumulate
#define BN_ACC(vv) { \
        h2v a0 = *(h2v*)&vv.x, a1 = *(h2v*)&vv.y; \
        a0 = __builtin_elementwise_max(a0 * sch0 + bih0, hz); \
        a1 = __builtin_elementwise_max(a1 * sch1 + bih1, hz); \
        ax += (float)a0.x; ay += (float)a0.y; az += (float)a1.x; aw += (float)a1.y; }

    for (int tile = blockIdx.x; tile < ntiles; tile += GRID_SG) {
        int n = tile * 32 + ni;
        float ax = 0.f, ay = 0.f, az = 0.f, aw = 0.f;
        int r0 = row_ptr[n], r1 = row_ptr[n + 1];
        int e = r0;
        for (; e + 8 <= r1; e += 8) {
            int s0 = csr_src[e],     s1 = csr_src[e + 1], s2 = csr_src[e + 2], s3 = csr_src[e + 3];
            int s4 = csr_src[e + 4], s5 = csr_src[e + 5], s6 = csr_src[e + 6], s7 = csr_src[e + 7];
            uint2 v0 = tbl[(size_t)s0 * 16 + g];
            uint2 v1 = tbl[(size_t)s1 * 16 + g];
            uint2 v2 = tbl[(size_t)s2 * 16 + g];
            uint2 v3 = tbl[(size_t)s3 * 16 + g];
            uint2 v4 = tbl[(size_t)s4 * 16 + g];
            uint2 v5 = tbl[(size_t)s5 * 16 + g];
            uint2 v6 = tbl[(size_t)s6 * 16 + g];
            uint2 v7 = tbl[(size_t)s7 * 16 + g];
            BN_ACC(v0) BN_ACC(v1) BN_ACC(v2) BN_ACC(v3)
            BN_ACC(v4) BN_ACC(v5) BN_ACC(v6) BN_ACC(v7)
        }
        for (; e < r1; ++e) {
            int s = csr_src[e];
            uint2 vv = tbl[(size_t)s * 16 + g];
            BN_ACC(vv)
        }
        float di = deg_inv[n];
        uint2 rsv = tbl[(size_t)n * 16 + g];
        h2v xs0h = __builtin_elementwise_max(*(h2v*)&rsv.x * sch0 + bih0, hz);
        h2v xs1h = __builtin_elementwise_max(*(h2v*)&rsv.y * sch1 + bih1, hz);
        ax *= di; ay *= di; az *= di; aw *= di;
        tAh[ni][2 * g]     = h2v{(_Float16)ax, (_Float16)ay};
        tAh[ni][2 * g + 1] = h2v{(_Float16)az, (_Float16)aw};
        tXh[ni][2 * g]     = xs0h;
        tXh[ni][2 * g + 1] = xs1h;
        __syncthreads();

        float4 o = ((const float4*)bl)[g];
#pragma unroll 4
        for (int kk = 0; kk < 32; kk++) {
            h2v a2 = tAh[ni][kk];
            h2v x2 = tXh[ni][kk];
            h2v l0 = wl2s[kk][4 * g + 0], l1 = wl2s[kk][4 * g + 1];
            h2v l2 = wl2s[kk][4 * g + 2], l3 = wl2s[kk][4 * g + 3];
            h2v r0v = wr2s[kk][4 * g + 0], r1v = wr2s[kk][4 * g + 1];
            h2v r2v = wr2s[kk][4 * g + 2], r3v = wr2s[kk][4 * g + 3];
#if __has_builtin(__builtin_amdgcn_fdot2)
            o.x = __builtin_amdgcn_fdot2(a2, l0, o.x, false);
            o.y = __builtin_amdgcn_fdot2(a2, l1, o.y, false);
            o.z = __builtin_amdgcn_fdot2(a2, l2, o.z, false);
            o.w = __builtin_amdgcn_fdot2(a2, l3, o.w, false);
            o.x = __builtin_amdgcn_fdot2(x2, r0v, o.x, false);
            o.y = __builtin_amdgcn_fdot2(x2, r1v, o.y, false);
            o.z = __builtin_amdgcn_fdot2(x2, r2v, o.z, false);
            o.w = __builtin_amdgcn_fdot2(x2, r3v, o.w, false);
#else
            float b0 = (float)a2.x, b1 = (float)a2.y, x0 = (float)x2.x, x1 = (float)x2.y;
            o.x += b0 * (float)l0.x + b1 * (float)l0.y + x0 * (float)r0v.x + x1 * (float)r0v.y;
            o.y += b0 * (float)l1.x + b1 * (float)l1.y + x0 * (float)r1v.x + x1 * (float)r1v.y;
            o.z += b0 * (float)l2.x + b1 * (float)l2.y + x0 * (float)r2v.x + x1 * (float)r2v.y;
            o.w += b0 * (float)l3.x + b1 * (float)l3.y + x0 * (float)r3v.x + x1 * (float)r3v.y;
#endif
        }
        {
            h2v p0 = h2v{(_Float16)o.x, (_Float16)o.y};
            h2v p1 = h2v{(_Float16)o.z, (_Float16)o.w};
            u32x2 w;
            w.x = *(unsigned int*)&p0;
            w.y = *(unsigned int*)&p1;
            __builtin_nontemporal_store(w, (u32x2*)hp16 + (size_t)n * 16 + g);
        }

        float4 qv = make_float4(o.x * o.x, o.y * o.y, o.z * o.z, o.w * o.w);
#pragma unroll
        for (int m = 16; m <= 32; m <<= 1) {
            o.x += __shfl_xor(o.x, m); o.y += __shfl_xor(o.y, m);
            o.z += __shfl_xor(o.z, m); o.w += __shfl_xor(o.w, m);
            qv.x += __shfl_xor(qv.x, m); qv.y += __shfl_xor(qv.y, m);
            qv.z += __shfl_xor(qv.z, m); qv.w += __shfl_xor(qv.w, m);
        }
        if ((tid & 48) == 0) {
            atomicAdd(&ssum[4 * g + 0], o.x); atomicAdd(&ssum[4 * g + 1], o.y);
            atomicAdd(&ssum[4 * g + 2], o.z); atomicAdd(&ssum[4 * g + 3], o.w);
            atomicAdd(&ssq[4 * g + 0], qv.x);  atomicAdd(&ssq[4 * g + 1], qv.y);
            atomicAdd(&ssq[4 * g + 2], qv.z);  atomicAdd(&ssq[4 * g + 3], qv.w);
        }
        __syncthreads();   // protect tAh/tXh for next tile
    }
#undef BN_ACC
    if (tid < 64) {
        part[(2 * tid) * PBMAX + blockIdx.x]     = ssum[tid];
        part[(2 * tid + 1) * PBMAX + blockIdx.x] = ssq[tid];
    }
}

// ---------------- reduce partials -> BN scale/bias ----------------
__global__ void k_reduce_sb(const float* __restrict__ part, int PB,
                            const float* __restrict__ gamma, const float* __restrict__ beta,
                            float* __restrict__ sbv, int N) {
    int c = blockIdx.x;
    float s = 0.f, q = 0.f;
    for (int b = threadIdx.x; b < PB; b += 256) {
        s += part[(2 * c) * PBMAX + b];
        q += part[(2 * c + 1) * PBMAX + b];
    }
    __shared__ float rs[256], rq[256];
    rs[threadIdx.x] = s;
    rq[threadIdx.x] = q;
    __syncthreads();
    for (int off = 128; off > 0; off >>= 1) {
        if (threadIdx.x < off) {
            rs[threadIdx.x] += rs[threadIdx.x + off];
            rq[threadIdx.x] += rq[threadIdx.x + off];
        }
        __syncthreads();
    }
    if (threadIdx.x == 0) {
        float m = rs[0] / (float)N;
        float var = rq[0] / (float)N - m * m;
        float sc = gamma[c] * rsqrtf(var + BN_EPS);
        sbv[c]      = sc;
        sbv[64 + c] = beta[c] - m * sc;
    }
}

// ---------------- pool partials: 8 slices x 128 graphs, BN3+ReLU inline ----------------
__global__ void __launch_bounds__(256) k_pool_partial(
    const __half* __restrict__ hp16, const float* __restrict__ sbv,
    const int* __restrict__ batch, float* __restrict__ pooled_part, int N) {
    __shared__ float ssc[64], sbi[64];
    __shared__ float sm[256];
    if (threadIdx.x < 64) {
        ssc[threadIdx.x] = sbv[threadIdx.x];
        sbi[threadIdx.x] = sbv[64 + threadIdx.x];
    }
    __syncthreads();
    int gph = blockIdx.x >> 3;        // 128 graphs
    int slice = blockIdx.x & 7;       // 8 slices
    int lo = 0, hi = N;
    while (lo < hi) { int mid = (lo + hi) >> 1; if (batch[mid] < gph) lo = mid + 1; else hi = mid; }
    int start = lo;
    hi = N;
    while (lo < hi) { int mid = (lo + hi) >> 1; if (batch[mid] < gph + 1) lo = mid + 1; else hi = mid; }
    int end = lo;

    int c = threadIdx.x & 63, w = threadIdx.x >> 6;   // 4 walkers/block, 32 grid-wide/graph
    float s = 0.f;
    for (int r = start + slice * 4 + w; r < end; r += 32)
        s += fmaxf(__half2float(hp16[(size_t)r * 64 + c]) * ssc[c] + sbi[c], 0.f);
    sm[threadIdx.x] = s;
    __syncthreads();
    if (threadIdx.x < 64) {
        float t = sm[c] + sm[64 + c] + sm[128 + c] + sm[192 + c];
        pooled_part[(size_t)(gph * PSLICE + slice) * 64 + c] = t;
    }
}

// ---------------- head: fold slice partials + MLP ----------------
__global__ void __launch_bounds__(64) k_head(
    const float* __restrict__ pooled_part, const int* __restrict__ batch,
    const float* __restrict__ fc1w, const float* __restrict__ fc1b,
    const float* __restrict__ fc2w, const float* __restrict__ fc2b,
    float* __restrict__ out, int N) {
    __shared__ float pl[64], hid[64];
    int gph = blockIdx.x;
    int j = threadIdx.x;
    int lo = 0, hi = N;
    while (lo < hi) { int mid = (lo + hi) >> 1; if (batch[mid] < gph) lo = mid + 1; else hi = mid; }
    int start = lo;
    hi = N;
    while (lo < hi) { int mid = (lo + hi) >> 1; if (batch[mid] < gph + 1) lo = mid + 1; else hi = mid; }
    int cnt = lo - start;

    float t = 0.f;
#pragma unroll
    for (int s = 0; s < PSLICE; s++) t += pooled_part[(size_t)(gph * PSLICE + s) * 64 + j];
    pl[j] = t / fmaxf((float)cnt, 1.0f);
    __syncthreads();
    float v = fc1b[j];
    for (int k = 0; k < 64; k++) v += pl[k] * fc1w[j * 64 + k];
    hid[j] = fmaxf(v, 0.f);
    __syncthreads();
    if (j < 2) {
        float o = fc2b[j];
        for (int k = 0; k < 64; k++) o += hid[k] * fc2w[j * 64 + k];
        out[gph * 2 + j] = o;
    }
}

extern "C" void kernel_launch(void* const* d_in, const int* in_sizes, int n_in,
                              void* d_out, int out_size, void* d_ws, size_t ws_size,
                              hipStream_t stream) {
    const float* x    = (const float*)d_in[0];
    const int* ei     = (const int*)d_in[1];
    const int* batch  = (const int*)d_in[2];
    const float* w1l  = (const float*)d_in[3];
    const float* b1   = (const float*)d_in[4];
    const float* w1r  = (const float*)d_in[5];
    const float* bn1g = (const float*)d_in[6];
    const float* bn1b = (const float*)d_in[7];
    const float* w2l  = (const float*)d_in[8];
    const float* b2   = (const float*)d_in[9];
    const float* w2r  = (const float*)d_in[10];
    const float* bn2g = (const float*)d_in[11];
    const float* bn2b = (const float*)d_in[12];
    const float* w3l  = (const float*)d_in[13];
    const float* b3   = (const float*)d_in[14];
    const float* w3r  = (const float*)d_in[15];
    const float* bn3g = (const float*)d_in[16];
    const float* bn3b = (const float*)d_in[17];
    const float* fc1w = (const float*)d_in[18];
    const float* fc1b = (const float*)d_in[19];
    const float* fc2w = (const float*)d_in[20];
    const float* fc2b = (const float*)d_in[21];
    float* out = (float*)d_out;

    const int N = NN, E = NE;
    const int* srcp = ei;
    const int* dstp = ei + E;

    char* ws = (char*)d_ws;
    size_t off = 0;
    auto alloc = [&](size_t bytes) -> char* {
        char* p = ws + off;
        off += (bytes + 255) & ~(size_t)255;
        return p;
    };
    int* csr_src       = (int*)alloc(sizeof(int) * E);
    __half* hpA        = (__half*)alloc(sizeof(__half) * N * 64); // pre-BN fp16 ping
    __half* hpB        = (__half*)alloc(sizeof(__half) * N * 64); // pre-BN fp16 pong
    unsigned int* slab = (unsigned int*)alloc(sizeof(unsigned int) * (size_t)NBUK * BCAP);
    int* slab_cursor   = (int*)alloc(sizeof(int) * NBUK);
    int* row_ptr       = (int*)alloc(sizeof(int) * (N + 1));
    float* deg_inv     = (float*)alloc(sizeof(float) * N);
    float* part        = (float*)alloc(sizeof(float) * 128 * PBMAX);
    float* sbv         = (float*)alloc(sizeof(float) * 128);
    float* pooled_part = (float*)alloc(sizeof(float) * NG * PSLICE * 64);

    hipMemsetAsync(slab_cursor, 0, sizeof(int) * NBUK, stream);

    // ---- CSR build + fused layer 1 -> hpA (pre-BN1) ----
    k_scatter<<<512, 512, 0, stream>>>(srcp, dstp, slab_cursor, slab, E);
    k_bucket_csr<<<NBUK, 512, 0, stream>>>(slab, slab_cursor, row_ptr, deg_inv,
                                           csr_src, x, w1l, b1, w1r, hpA, part);
    k_reduce_sb<<<64, 256, 0, stream>>>(part, NBUK, bn1g, bn1b, sbv, N);

    // layer 2: BN1+ReLU in-gather from hpA -> hpB (pre-BN2)
    k_sage<<<GRID_SG, 512, 0, stream>>>(hpA, sbv, row_ptr, csr_src, deg_inv,
                                        w2l, b2, w2r, hpB, part);
    k_reduce_sb<<<64, 256, 0, stream>>>(part, GRID_SG, bn2g, bn2b, sbv, N);

    // layer 3: BN2+ReLU in-gather from hpB -> hpA (pre-BN3)
    k_sage<<<GRID_SG, 512, 0, stream>>>(hpB, sbv, row_ptr, csr_src, deg_inv,
                                        w3l, b3, w3r, hpA, part);
    k_reduce_sb<<<64, 256, 0, stream>>>(part, GRID_SG, bn3g, bn3b, sbv, N);

    // pool (BN3+ReLU inline) + head
    k_pool_partial<<<NG * PSLICE, 256, 0, stream>>>(hpA, sbv, batch, pooled_part, N);
    k_head<<<NG, 64, 0, stream>>>(pooled_part, batch, fc1w, fc1b, fc2w, fc2b, out, N);
}

// Round 18
// 375.249 us; speedup vs baseline: 1.0684x; 1.0510x over previous
//
#include <hip/hip_runtime.h>
#include <hip/hip_fp16.h>

#define NN 100000
#define NE 3200000
#define NG 128
#define BN_EPS 1e-5f

#define NBUK 782          // ceil(100000 / 128)
#define BSHIFT 7          // bucket = dst >> 7 (128 nodes per bucket)
#define BCAP 6144         // slab capacity per bucket (mean 4096, +32 sigma)

#define GRID_SG 1024      // persistent blocks, 4/CU
#define PBMAX 2048        // partial-buffer column stride
#define PSLICE 8          // pool slices per graph

typedef _Float16 h2v __attribute__((ext_vector_type(2)));
typedef unsigned int u32x2 __attribute__((ext_vector_type(2)));
typedef unsigned int u32x4 __attribute__((ext_vector_type(4)));

// Lessons ledger:
// r9: no grid-wide spin barriers. r10: no device fences in gather kernels.
// r12: nt only full-line write-once / read-once streams.
// r13: nt-data consumers need block parallelism.
// r14: FETCH == L2-miss traffic; table at ~60% L2-hit equilibrium.
// r15/r17: BN-in-gather VALU cost -> packed fp16; f32 unpack-acc was the
//          residual term -> r18 pair-accumulates in fp16, flushes every 8.

// ---------------- bucketed edge scatter (counting-sort level 1) ----------------
// 256 blocks: halves same-address serialization on slab_cursor reservations.
__global__ void __launch_bounds__(512) k_scatter(
    const int* __restrict__ src, const int* __restrict__ dst,
    int* __restrict__ slab_cursor, unsigned int* __restrict__ slab, int E) {
    __shared__ int hist[NBUK + 2];
    __shared__ int cbase[NBUK + 2];
    int tid = threadIdx.x;
    int eBeg = blockIdx.x * 12500;
    int eEnd = min(eBeg + 12500, E);

    for (int t = tid; t < NBUK; t += 512) hist[t] = 0;
    __syncthreads();
    for (int e = eBeg + tid; e < eEnd; e += 512) {
        int b = dst[e] >> BSHIFT;
        atomicAdd(&hist[b], 1);
    }
    __syncthreads();
    for (int t = tid; t < NBUK; t += 512) {
        int c = hist[t];
        cbase[t] = (c > 0) ? atomicAdd(&slab_cursor[t], c) : 0;
    }
    __syncthreads();
    for (int t = tid; t < NBUK; t += 512) hist[t] = 0;
    __syncthreads();
    for (int e = eBeg + tid; e < eEnd; e += 512) {
        int d = dst[e];
        int b = d >> BSHIFT;
        int r = atomicAdd(&hist[b], 1);
        int pos = cbase[b] + r;
        if (pos < BCAP) slab[(size_t)b * BCAP + pos] = ((unsigned)src[e] << BSHIFT) | (unsigned)(d & 127);
    }
}

// ---------------- per-bucket CSR build + FUSED LAYER 1 (scan folded in) ----------------
// Slab read ONCE into registers (<=12/thread); histogram + scatter from registers.
__global__ void __launch_bounds__(512) k_bucket_csr(
    const unsigned int* __restrict__ slab, const int* __restrict__ slab_cursor,
    int* __restrict__ row_ptr,
    float* __restrict__ deg_inv, int* __restrict__ csr_src,
    const float* __restrict__ x, const float* __restrict__ w1l,
    const float* __restrict__ b1, const float* __restrict__ w1r,
    __half* __restrict__ hp16, float* __restrict__ part) {
    __shared__ int lds_csr[BCAP];
    __shared__ int red[512];
    __shared__ int sdeg[128];
    __shared__ int sscan[128];
    __shared__ int slcur[128];
    __shared__ float swl[256], swr[256], sb1[64];
    __shared__ float ssum[64], ssq[64];
    int tid = threadIdx.x;
    int b = blockIdx.x;
    int lo = b << BSHIFT;
    int cnt = min(slab_cursor[b], BCAP);
    const unsigned int* sl = slab + (size_t)b * BCAP;

    // inline exclusive prefix over bucket counts
    int partial = 0;
    for (int j = tid; j < b; j += 512) partial += min(slab_cursor[j], BCAP);
    red[tid] = partial;
    __syncthreads();
    for (int off = 256; off > 0; off >>= 1) {
        if (tid < off) red[tid] += red[tid + off];
        __syncthreads();
    }
    int base = red[0];
    if (b == NBUK - 1 && tid == 0) row_ptr[NN] = base + cnt;

    if (tid < 256) { swl[tid] = w1l[tid]; swr[tid] = w1r[tid]; }
    if (tid < 64)  { sb1[tid] = b1[tid]; ssum[tid] = 0.f; ssq[tid] = 0.f; }
    if (tid < 128) sdeg[tid] = 0;
    __syncthreads();

    // single global pass: stage slab entries in registers
    unsigned int myv[12];
    int mycount = 0;
    for (int k = tid; k < cnt; k += 512) myv[mycount++] = sl[k];
#pragma unroll
    for (int j = 0; j < 12; j++)
        if (j < mycount) atomicAdd(&sdeg[myv[j] & 127], 1);
    __syncthreads();
    int v = (tid < 128) ? sdeg[tid] : 0;
    if (tid < 128) sscan[tid] = v;
    __syncthreads();
    for (int off = 1; off < 128; off <<= 1) {
        int add = 0;
        if (tid < 128 && tid >= off) add = sscan[tid - off];
        __syncthreads();
        if (tid < 128) sscan[tid] += add;
        __syncthreads();
    }
    if (tid < 128) {
        int excl = sscan[tid] - v;
        int n = lo + tid;
        if (n < NN) {
            row_ptr[n] = base + excl;
            deg_inv[n] = 1.0f / fmaxf((float)v, 1.0f);
        }
        slcur[tid] = excl;   // LOCAL cursor
    }
    __syncthreads();
#pragma unroll
    for (int j = 0; j < 12; j++)
        if (j < mycount) {
            unsigned int p = myv[j];
            int pos = atomicAdd(&slcur[p & 127], 1);
            lds_csr[pos] = (int)(p >> BSHIFT);
        }
    __syncthreads();
    // cached store: csr_src re-read by both k_sage layers
    for (int k = tid; k < cnt; k += 512) csr_src[base + k] = lds_csr[k];

    // ---- Phase B: layer 1 (x-gather 4-deep pipelined) ----
    int i = tid >> 2, c = tid & 3;
    int n = lo + i;
    bool valid = (n < NN);
    int dhi = sscan[i];
    int dlo = dhi - sdeg[i];
    const float4* x4 = (const float4*)x;
    float4 acc = make_float4(0.f, 0.f, 0.f, 0.f);
    int k = dlo + c;
    for (; k + 12 < dhi; k += 16) {
        int s0 = lds_csr[k], s1 = lds_csr[k + 4], s2 = lds_csr[k + 8], s3 = lds_csr[k + 12];
        float4 v0 = x4[s0];
        float4 v1 = x4[s1];
        float4 v2 = x4[s2];
        float4 v3 = x4[s3];
        acc.x += v0.x + v1.x + v2.x + v3.x;
        acc.y += v0.y + v1.y + v2.y + v3.y;
        acc.z += v0.z + v1.z + v2.z + v3.z;
        acc.w += v0.w + v1.w + v2.w + v3.w;
    }
    for (; k < dhi; k += 4) {
        int s = lds_csr[k];
        float4 xv = x4[s];
        acc.x += xv.x; acc.y += xv.y; acc.z += xv.z; acc.w += xv.w;
    }
#pragma unroll
    for (int m = 1; m <= 2; m <<= 1) {
        acc.x += __shfl_xor(acc.x, m);
        acc.y += __shfl_xor(acc.y, m);
        acc.z += __shfl_xor(acc.z, m);
        acc.w += __shfl_xor(acc.w, m);
    }
    float dv = 1.0f / fmaxf((float)sdeg[i], 1.0f);
    float ax = acc.x * dv, ay = acc.y * dv, az = acc.z * dv, aw = acc.w * dv;
    float4 xs = valid ? x4[n] : make_float4(0.f, 0.f, 0.f, 0.f);

#pragma unroll
    for (int m4 = 0; m4 < 4; m4++) {
        float4 o = make_float4(0.f, 0.f, 0.f, 0.f);
        float* op = &o.x;
        if (valid) {
#pragma unroll
            for (int t = 0; t < 4; t++) {
                int j = c * 16 + m4 * 4 + t;
                float s = sb1[j];
                s += ax * swl[j * 4 + 0] + ay * swl[j * 4 + 1] + az * swl[j * 4 + 2] + aw * swl[j * 4 + 3];
                s += xs.x * swr[j * 4 + 0] + xs.y * swr[j * 4 + 1] + xs.z * swr[j * 4 + 2] + xs.w * swr[j * 4 + 3];
                op[t] = s;
            }
            h2v p0 = h2v{(_Float16)o.x, (_Float16)o.y};
            h2v p1 = h2v{(_Float16)o.z, (_Float16)o.w};
            u32x2 w;
            w.x = *(unsigned int*)&p0;
            w.y = *(unsigned int*)&p1;
            __builtin_nontemporal_store(w, (u32x2*)hp16 + (size_t)n * 16 + c * 4 + m4);
        }
        float4 q = make_float4(o.x * o.x, o.y * o.y, o.z * o.z, o.w * o.w);
#pragma unroll
        for (int m = 4; m <= 32; m <<= 1) {
            o.x += __shfl_xor(o.x, m); o.y += __shfl_xor(o.y, m);
            o.z += __shfl_xor(o.z, m); o.w += __shfl_xor(o.w, m);
            q.x += __shfl_xor(q.x, m); q.y += __shfl_xor(q.y, m);
            q.z += __shfl_xor(q.z, m); q.w += __shfl_xor(q.w, m);
        }
        if ((tid & 63) < 4) {
            int jb = c * 16 + m4 * 4;
            atomicAdd(&ssum[jb + 0], o.x); atomicAdd(&ssum[jb + 1], o.y);
            atomicAdd(&ssum[jb + 2], o.z); atomicAdd(&ssum[jb + 3], o.w);
            atomicAdd(&ssq[jb + 0], q.x);  atomicAdd(&ssq[jb + 1], q.y);
            atomicAdd(&ssq[jb + 2], q.z);  atomicAdd(&ssq[jb + 3], q.w);
        }
    }
    __syncthreads();
    if (tid < 64) {
        part[(2 * tid) * PBMAX + blockIdx.x]     = ssum[tid];
        part[(2 * tid + 1) * PBMAX + blockIdx.x] = ssq[tid];
    }
}

// ---------------- fused SAGE layer: packed BN+ReLU + fp16 pair-accumulate ----------------
__global__ void __launch_bounds__(512, 8) k_sage(
    const __half* __restrict__ h_in, const float* __restrict__ sbv_in,
    const int* __restrict__ row_ptr,
    const int* __restrict__ csr_src, const float* __restrict__ deg_inv,
    const float* __restrict__ wl, const float* __restrict__ bl,
    const float* __restrict__ wr, __half* __restrict__ hp16,
    float* __restrict__ part) {
    __shared__ h2v wl2s[32][68];   // [k-pair][out-channel]
    __shared__ h2v wr2s[32][68];
    __shared__ h2v tAh[32][36];
    __shared__ h2v tXh[32][36];
    __shared__ float ssum[64], ssq[64];
    int tid = threadIdx.x;
    for (int idx = tid; idx < 2048; idx += 512) {
        int j = idx & 63, kk = idx >> 6;
        float2 l = ((const float2*)wl)[j * 32 + kk];
        float2 r = ((const float2*)wr)[j * 32 + kk];
        wl2s[kk][j] = h2v{(_Float16)l.x, (_Float16)l.y};
        wr2s[kk][j] = h2v{(_Float16)r.x, (_Float16)r.y};
    }
    if (tid < 64) { ssum[tid] = 0.f; ssq[tid] = 0.f; }
    __syncthreads();

    int g = tid & 15, ni = tid >> 4;      // ni in [0,32)
    h2v sch0 = h2v{(_Float16)sbv_in[4 * g + 0], (_Float16)sbv_in[4 * g + 1]};
    h2v sch1 = h2v{(_Float16)sbv_in[4 * g + 2], (_Float16)sbv_in[4 * g + 3]};
    h2v bih0 = h2v{(_Float16)sbv_in[64 + 4 * g + 0], (_Float16)sbv_in[64 + 4 * g + 1]};
    h2v bih1 = h2v{(_Float16)sbv_in[64 + 4 * g + 2], (_Float16)sbv_in[64 + 4 * g + 3]};
    h2v hz = h2v{(_Float16)0.f, (_Float16)0.f};

    const uint2* tbl = (const uint2*)h_in;
    const int ntiles = NN / 32;           // 3125 exactly

    // packed BN+ReLU into fp16 pair-accumulators (flushed to f32 every 8 edges)
#define BN_ACC_H(vv) { \
        h2v a0 = *(h2v*)&vv.x, a1 = *(h2v*)&vv.y; \
        hacc0 += __builtin_elementwise_max(a0 * sch0 + bih0, hz); \
        hacc1 += __builtin_elementwise_max(a1 * sch1 + bih1, hz); }

    for (int tile = blockIdx.x; tile < ntiles; tile += GRID_SG) {
        int n = tile * 32 + ni;
        float ax = 0.f, ay = 0.f, az = 0.f, aw = 0.f;
        int r0 = row_ptr[n], r1 = row_ptr[n + 1];
        int e = r0;
        for (; e + 8 <= r1; e += 8) {
            int s0 = csr_src[e],     s1 = csr_src[e + 1], s2 = csr_src[e + 2], s3 = csr_src[e + 3];
            int s4 = csr_src[e + 4], s5 = csr_src[e + 5], s6 = csr_src[e + 6], s7 = csr_src[e + 7];
            uint2 v0 = tbl[(size_t)s0 * 16 + g];
            uint2 v1 = tbl[(size_t)s1 * 16 + g];
            uint2 v2 = tbl[(size_t)s2 * 16 + g];
            uint2 v3 = tbl[(size_t)s3 * 16 + g];
            uint2 v4 = tbl[(size_t)s4 * 16 + g];
            uint2 v5 = tbl[(size_t)s5 * 16 + g];
            uint2 v6 = tbl[(size_t)s6 * 16 + g];
            uint2 v7 = tbl[(size_t)s7 * 16 + g];
            h2v hacc0 = hz, hacc1 = hz;
            BN_ACC_H(v0) BN_ACC_H(v1) BN_ACC_H(v2) BN_ACC_H(v3)
            BN_ACC_H(v4) BN_ACC_H(v5) BN_ACC_H(v6) BN_ACC_H(v7)
            ax += (float)hacc0.x; ay += (float)hacc0.y;
            az += (float)hacc1.x; aw += (float)hacc1.y;
        }
        for (; e < r1; ++e) {
            int s = csr_src[e];
            uint2 vv = tbl[(size_t)s * 16 + g];
            h2v a0 = *(h2v*)&vv.x, a1 = *(h2v*)&vv.y;
            a0 = __builtin_elementwise_max(a0 * sch0 + bih0, hz);
            a1 = __builtin_elementwise_max(a1 * sch1 + bih1, hz);
            ax += (float)a0.x; ay += (float)a0.y; az += (float)a1.x; aw += (float)a1.y;
        }
        float di = deg_inv[n];
        uint2 rsv = tbl[(size_t)n * 16 + g];
        h2v xs0h = __builtin_elementwise_max(*(h2v*)&rsv.x * sch0 + bih0, hz);
        h2v xs1h = __builtin_elementwise_max(*(h2v*)&rsv.y * sch1 + bih1, hz);
        ax *= di; ay *= di; az *= di; aw *= di;
        tAh[ni][2 * g]     = h2v{(_Float16)ax, (_Float16)ay};
        tAh[ni][2 * g + 1] = h2v{(_Float16)az, (_Float16)aw};
        tXh[ni][2 * g]     = xs0h;
        tXh[ni][2 * g + 1] = xs1h;
        __syncthreads();

        float4 o = ((const float4*)bl)[g];
#pragma unroll 4
        for (int kk = 0; kk < 32; kk++) {
            h2v a2 = tAh[ni][kk];
            h2v x2 = tXh[ni][kk];
            h2v l0 = wl2s[kk][4 * g + 0], l1 = wl2s[kk][4 * g + 1];
            h2v l2 = wl2s[kk][4 * g + 2], l3 = wl2s[kk][4 * g + 3];
            h2v r0v = wr2s[kk][4 * g + 0], r1v = wr2s[kk][4 * g + 1];
            h2v r2v = wr2s[kk][4 * g + 2], r3v = wr2s[kk][4 * g + 3];
#if __has_builtin(__builtin_amdgcn_fdot2)
            o.x = __builtin_amdgcn_fdot2(a2, l0, o.x, false);
            o.y = __builtin_amdgcn_fdot2(a2, l1, o.y, false);
            o.z = __builtin_amdgcn_fdot2(a2, l2, o.z, false);
            o.w = __builtin_amdgcn_fdot2(a2, l3, o.w, false);
            o.x = __builtin_amdgcn_fdot2(x2, r0v, o.x, false);
            o.y = __builtin_amdgcn_fdot2(x2, r1v, o.y, false);
            o.z = __builtin_amdgcn_fdot2(x2, r2v, o.z, false);
            o.w = __builtin_amdgcn_fdot2(x2, r3v, o.w, false);
#else
            float b0 = (float)a2.x, b1 = (float)a2.y, x0 = (float)x2.x, x1 = (float)x2.y;
            o.x += b0 * (float)l0.x + b1 * (float)l0.y + x0 * (float)r0v.x + x1 * (float)r0v.y;
            o.y += b0 * (float)l1.x + b1 * (float)l1.y + x0 * (float)r1v.x + x1 * (float)r1v.y;
            o.z += b0 * (float)l2.x + b1 * (float)l2.y + x0 * (float)r2v.x + x1 * (float)r2v.y;
            o.w += b0 * (float)l3.x + b1 * (float)l3.y + x0 * (float)r3v.x + x1 * (float)r3v.y;
#endif
        }
        {
            h2v p0 = h2v{(_Float16)o.x, (_Float16)o.y};
            h2v p1 = h2v{(_Float16)o.z, (_Float16)o.w};
            u32x2 w;
            w.x = *(unsigned int*)&p0;
            w.y = *(unsigned int*)&p1;
            __builtin_nontemporal_store(w, (u32x2*)hp16 + (size_t)n * 16 + g);
        }

        float4 qv = make_float4(o.x * o.x, o.y * o.y, o.z * o.z, o.w * o.w);
#pragma unroll
        for (int m = 16; m <= 32; m <<= 1) {
            o.x += __shfl_xor(o.x, m); o.y += __shfl_xor(o.y, m);
            o.z += __shfl_xor(o.z, m); o.w += __shfl_xor(o.w, m);
            qv.x += __shfl_xor(qv.x, m); qv.y += __shfl_xor(qv.y, m);
            qv.z += __shfl_xor(qv.z, m); qv.w += __shfl_xor(qv.w, m);
        }
        if ((tid & 48) == 0) {
            atomicAdd(&ssum[4 * g + 0], o.x); atomicAdd(&ssum[4 * g + 1], o.y);
            atomicAdd(&ssum[4 * g + 2], o.z); atomicAdd(&ssum[4 * g + 3], o.w);
            atomicAdd(&ssq[4 * g + 0], qv.x);  atomicAdd(&ssq[4 * g + 1], qv.y);
            atomicAdd(&ssq[4 * g + 2], qv.z);  atomicAdd(&ssq[4 * g + 3], qv.w);
        }
        __syncthreads();   // protect tAh/tXh for next tile
    }
#undef BN_ACC_H
    if (tid < 64) {
        part[(2 * tid) * PBMAX + blockIdx.x]     = ssum[tid];
        part[(2 * tid + 1) * PBMAX + blockIdx.x] = ssq[tid];
    }
}

// ---------------- reduce partials -> BN scale/bias ----------------
__global__ void k_reduce_sb(const float* __restrict__ part, int PB,
                            const float* __restrict__ gamma, const float* __restrict__ beta,
                            float* __restrict__ sbv, int N) {
    int c = blockIdx.x;
    float s = 0.f, q = 0.f;
    for (int b = threadIdx.x; b < PB; b += 256) {
        s += part[(2 * c) * PBMAX + b];
        q += part[(2 * c + 1) * PBMAX + b];
    }
    __shared__ float rs[256], rq[256];
    rs[threadIdx.x] = s;
    rq[threadIdx.x] = q;
    __syncthreads();
    for (int off = 128; off > 0; off >>= 1) {
        if (threadIdx.x < off) {
            rs[threadIdx.x] += rs[threadIdx.x + off];
            rq[threadIdx.x] += rq[threadIdx.x + off];
        }
        __syncthreads();
    }
    if (threadIdx.x == 0) {
        float m = rs[0] / (float)N;
        float var = rq[0] / (float)N - m * m;
        float sc = gamma[c] * rsqrtf(var + BN_EPS);
        sbv[c]      = sc;
        sbv[64 + c] = beta[c] - m * sc;
    }
}

// ---------------- pool partials: 8 slices x 128 graphs, BN3+ReLU inline ----------------
__global__ void __launch_bounds__(256) k_pool_partial(
    const __half* __restrict__ hp16, const float* __restrict__ sbv,
    const int* __restrict__ batch, float* __restrict__ pooled_part, int N) {
    __shared__ float ssc[64], sbi[64];
    __shared__ float sm[256];
    if (threadIdx.x < 64) {
        ssc[threadIdx.x] = sbv[threadIdx.x];
        sbi[threadIdx.x] = sbv[64 + threadIdx.x];
    }
    __syncthreads();
    int gph = blockIdx.x >> 3;        // 128 graphs
    int slice = blockIdx.x & 7;       // 8 slices
    int lo = 0, hi = N;
    while (lo < hi) { int mid = (lo + hi) >> 1; if (batch[mid] < gph) lo = mid + 1; else hi = mid; }
    int start = lo;
    hi = N;
    while (lo < hi) { int mid = (lo + hi) >> 1; if (batch[mid] < gph + 1) lo = mid + 1; else hi = mid; }
    int end = lo;

    int c = threadIdx.x & 63, w = threadIdx.x >> 6;   // 4 walkers/block, 32 grid-wide/graph
    float s = 0.f;
    for (int r = start + slice * 4 + w; r < end; r += 32)
        s += fmaxf(__half2float(hp16[(size_t)r * 64 + c]) * ssc[c] + sbi[c], 0.f);
    sm[threadIdx.x] = s;
    __syncthreads();
    if (threadIdx.x < 64) {
        float t = sm[c] + sm[64 + c] + sm[128 + c] + sm[192 + c];
        pooled_part[(size_t)(gph * PSLICE + slice) * 64 + c] = t;
    }
}

// ---------------- head: fold slice partials + MLP ----------------
__global__ void __launch_bounds__(64) k_head(
    const float* __restrict__ pooled_part, const int* __restrict__ batch,
    const float* __restrict__ fc1w, const float* __restrict__ fc1b,
    const float* __restrict__ fc2w, const float* __restrict__ fc2b,
    float* __restrict__ out, int N) {
    __shared__ float pl[64], hid[64];
    int gph = blockIdx.x;
    int j = threadIdx.x;
    int lo = 0, hi = N;
    while (lo < hi) { int mid = (lo + hi) >> 1; if (batch[mid] < gph) lo = mid + 1; else hi = mid; }
    int start = lo;
    hi = N;
    while (lo < hi) { int mid = (lo + hi) >> 1; if (batch[mid] < gph + 1) lo = mid + 1; else hi = mid; }
    int cnt = lo - start;

    float t = 0.f;
#pragma unroll
    for (int s = 0; s < PSLICE; s++) t += pooled_part[(size_t)(gph * PSLICE + s) * 64 + j];
    pl[j] = t / fmaxf((float)cnt, 1.0f);
    __syncthreads();
    float v = fc1b[j];
    for (int k = 0; k < 64; k++) v += pl[k] * fc1w[j * 64 + k];
    hid[j] = fmaxf(v, 0.f);
    __syncthreads();
    if (j < 2) {
        float o = fc2b[j];
        for (int k = 0; k < 64; k++) o += hid[k] * fc2w[j * 64 + k];
        out[gph * 2 + j] = o;
    }
}

extern "C" void kernel_launch(void* const* d_in, const int* in_sizes, int n_in,
                              void* d_out, int out_size, void* d_ws, size_t ws_size,
                              hipStream_t stream) {
    const float* x    = (const float*)d_in[0];
    const int* ei     = (const int*)d_in[1];
    const int* batch  = (const int*)d_in[2];
    const float* w1l  = (const float*)d_in[3];
    const float* b1   = (const float*)d_in[4];
    const float* w1r  = (const float*)d_in[5];
    const float* bn1g = (const float*)d_in[6];
    const float* bn1b = (const float*)d_in[7];
    const float* w2l  = (const float*)d_in[8];
    const float* b2   = (const float*)d_in[9];
    const float* w2r  = (const float*)d_in[10];
    const float* bn2g = (const float*)d_in[11];
    const float* bn2b = (const float*)d_in[12];
    const float* w3l  = (const float*)d_in[13];
    const float* b3   = (const float*)d_in[14];
    const float* w3r  = (const float*)d_in[15];
    const float* bn3g = (const float*)d_in[16];
    const float* bn3b = (const float*)d_in[17];
    const float* fc1w = (const float*)d_in[18];
    const float* fc1b = (const float*)d_in[19];
    const float* fc2w = (const float*)d_in[20];
    const float* fc2b = (const float*)d_in[21];
    float* out = (float*)d_out;

    const int N = NN, E = NE;
    const int* srcp = ei;
    const int* dstp = ei + E;

    char* ws = (char*)d_ws;
    size_t off = 0;
    auto alloc = [&](size_t bytes) -> char* {
        char* p = ws + off;
        off += (bytes + 255) & ~(size_t)255;
        return p;
    };
    int* csr_src       = (int*)alloc(sizeof(int) * E);
    __half* hpA        = (__half*)alloc(sizeof(__half) * N * 64); // pre-BN fp16 ping
    __half* hpB        = (__half*)alloc(sizeof(__half) * N * 64); // pre-BN fp16 pong
    unsigned int* slab = (unsigned int*)alloc(sizeof(unsigned int) * (size_t)NBUK * BCAP);
    int* slab_cursor   = (int*)alloc(sizeof(int) * NBUK);
    int* row_ptr       = (int*)alloc(sizeof(int) * (N + 1));
    float* deg_inv     = (float*)alloc(sizeof(float) * N);
    float* part        = (float*)alloc(sizeof(float) * 128 * PBMAX);
    float* sbv         = (float*)alloc(sizeof(float) * 128);
    float* pooled_part = (float*)alloc(sizeof(float) * NG * PSLICE * 64);

    hipMemsetAsync(slab_cursor, 0, sizeof(int) * NBUK, stream);

    // ---- CSR build + fused layer 1 -> hpA (pre-BN1) ----
    k_scatter<<<256, 512, 0, stream>>>(srcp, dstp, slab_cursor, slab, E);
    k_bucket_csr<<<NBUK, 512, 0, stream>>>(slab, slab_cursor, row_ptr, deg_inv,
                                           csr_src, x, w1l, b1, w1r, hpA, part);
    k_reduce_sb<<<64, 256, 0, stream>>>(part, NBUK, bn1g, bn1b, sbv, N);

    // layer 2: BN1+ReLU in-gather from hpA -> hpB (pre-BN2)
    k_sage<<<GRID_SG, 512, 0, stream>>>(hpA, sbv, row_ptr, csr_src, deg_inv,
                                        w2l, b2, w2r, hpB, part);
    k_reduce_sb<<<64, 256, 0, stream>>>(part, GRID_SG, bn2g, bn2b, sbv, N);

    // layer 3: BN2+ReLU in-gather from hpB -> hpA (pre-BN3)
    k_sage<<<GRID_SG, 512, 0, stream>>>(hpB, sbv, row_ptr, csr_src, deg_inv,
                                        w3l, b3, w3r, hpA, part);
    k_reduce_sb<<<64, 256, 0, stream>>>(part, GRID_SG, bn3g, bn3b, sbv, N);

    // pool (BN3+ReLU inline) + head
    k_pool_partial<<<NG * PSLICE, 256, 0, stream>>>(hpA, sbv, batch, pooled_part, N);
    k_head<<<NG, 64, 0, stream>>>(pooled_part, batch, fc1w, fc1b, fc2w, fc2b, out, N);
}